// Round 5
// baseline (317.241 us; speedup 1.0000x reference)
//
#include <hip/hip_runtime.h>

#define IN_SIZE 256
#define N_NODES 1024
#define DEG 32
#define BATCH 16384
#define OUT_SIZE 16
#define COLS 4                        // batch columns per single-wave block
#define N_ROWS (IN_SIZE + N_NODES)    // 1280 activation rows (fp32 in LDS)

// RNE float -> bf16
__device__ __forceinline__ unsigned short f2bf_rne(float f) {
    const unsigned u = __float_as_uint(f);
    return (unsigned short)((u + 0x7FFFu + ((u >> 16) & 1u)) >> 16);
}

// rotate-reduce add across the 16-lane DPP row: row_ror:N ctrl = 0x120|N.
// After stages 1,2,4,8 every lane of the row holds the full 16-lane sum.
template <int CTRL>
__device__ __forceinline__ float dpp_add(float v) {
    return v + __int_as_float(__builtin_amdgcn_mov_dpp(__float_as_int(v), CTRL, 0xF, 0xF, true));
}

// ---------------------------------------------------------------------------
// Runtime dtype detector (unchanged).
// ---------------------------------------------------------------------------
__global__ __launch_bounds__(64) void ne_detect(const void* __restrict__ xraw,
                                                int* __restrict__ flag) {
    const unsigned short* xb = (const unsigned short*)xraw;
    const int tid = threadIdx.x;
    int plausible = 0;
    for (int k = tid; k < 2048; k += 64) {
        const float v = __uint_as_float((unsigned)xb[2 * k] << 16);
        const float a = fabsf(v);
        plausible += (a == 0.0f) || (a > 1e-3f && a < 1e3f) ? 1 : 0;
    }
    for (int off = 32; off > 0; off >>= 1) plausible += __shfl_down(plausible, off);
    if (tid == 0) *flag = (plausible >= (2048 * 9) / 10) ? 1 : 0;
}

// ---------------------------------------------------------------------------
// Build packed node table pk[n][16] = {idx0, idx1, w0, w1} per fan-in pair
// (one dwordx4 refill per lane in the hot loop) plus hazard scalars hzr
// replicated x8 (per-lane vector load; a uniform-address load would become
// s_load -> lgkmcnt(0) drain of in-flight ds_reads, the round-3 stall).
//   h1[n] = sum w[n][k] where idx[n][k] == 256+n-1   (etc. h2, h3)
// ---------------------------------------------------------------------------
__global__ __launch_bounds__(256) void ne_prep(const void* __restrict__ wraw,
                                               const int* __restrict__ idxs,
                                               uint4* __restrict__ pk,
                                               float4* __restrict__ hzr,
                                               const int* __restrict__ flag) {
    const int isbf16 = *flag;                    // uniform
    const int tid = blockIdx.x * 256 + threadIdx.x;
    const int stride = gridDim.x * 256;
    const unsigned short* wb = (const unsigned short*)wraw;
    const float* wsrc = (const float*)wraw;
    for (int k = tid; k < N_NODES * 16; k += stride) {
        const int n = k >> 4, g = k & 15;
        const int e = n * DEG + 2 * g;
        const float w0 = isbf16 ? __uint_as_float((unsigned)wb[e] << 16) : wsrc[e];
        const float w1 = isbf16 ? __uint_as_float((unsigned)wb[e + 1] << 16) : wsrc[e + 1];
        pk[k] = make_uint4((unsigned)idxs[e], (unsigned)idxs[e + 1],
                           __float_as_uint(w0), __float_as_uint(w1));
    }
    for (int n = tid; n < N_NODES; n += stride) {
        float h1 = 0.0f, h2 = 0.0f, h3 = 0.0f;
        const int r1 = IN_SIZE + n - 1, r2 = IN_SIZE + n - 2, r3 = IN_SIZE + n - 3;
        for (int k = 0; k < DEG; ++k) {
            const int id = idxs[n * DEG + k];
            const float w = isbf16 ? __uint_as_float((unsigned)wb[n * DEG + k] << 16)
                                   : wsrc[n * DEG + k];
            if (n >= 1 && id == r1) h1 += w;
            if (n >= 2 && id == r2) h2 += w;
            if (n >= 3 && id == r3) h3 += w;
        }
        const float4 h = make_float4(h1, h2, h3, 0.0f);
#pragma unroll
        for (int r = 0; r < 8; ++r) hzr[n * 8 + r] = h;
    }
}

// ---------------------------------------------------------------------------
// fp32 LDS activations, COLS=4 (20 KB -> 8 single-wave blocks/CU = 2 waves
// per SIMD: independent waves hide each other's DS/VMEM stalls; columns are
// fully independent so there is STILL no barrier anywhere). Lane = c*16+q:
// q (bits 0-3) = fan-in pair group (elements 2q,2q+1), c (bits 4-5) = column.
// Per step i: reduce node i+1 (2 FMA + 4 row_ror DPP); issue gathers node
// i+3 (stale rows 256+i..i+2 pre-zeroed, folded back via h1..h3); finalize
// node i (h-FMAs + tanh); write; refill slot i&7 with node i+8 (2 vector
// loads: packed pk dwordx4 + hzr dwordx4, both vmcnt-tracked).
// ---------------------------------------------------------------------------
__global__ __launch_bounds__(64) void ne_forward(const void* __restrict__ xraw,
                                                 const uint4* __restrict__ pk,
                                                 const float4* __restrict__ hzr,
                                                 void* __restrict__ outraw,
                                                 const int* __restrict__ flag) {
    __shared__ float act[N_ROWS * COLS];         // 20480 B -> 8 blocks/CU
    const int lane = threadIdx.x;
    const int q = lane & 15;                     // fan-in pair group 0..15
    const int c = lane >> 4;                     // batch column 0..3
    const int c0 = blockIdx.x * COLS;
    const int isbf16 = *flag;                    // uniform
    float* outf = (float*)outraw;
    unsigned short* outb = (unsigned short*)outraw;

    // ---- zero node rows so stale gathers read exactly 0.0 ----
    {
        float4* az = (float4*)(act + IN_SIZE * COLS);   // 1024 float4
#pragma unroll
        for (int t = 0; t < 16; ++t) az[t * 64 + lane] = make_float4(0.f, 0.f, 0.f, 0.f);
    }
    // ---- seed input rows 0..255 from raw x: lane covers rows q*16..+15, col c ----
    {
        const int b = c;
        if (isbf16) {
            const unsigned short* xb =
                (const unsigned short*)xraw + (size_t)(c0 + b) * IN_SIZE + q * 16;
#pragma unroll
            for (int t = 0; t < 2; ++t) {
                const uint4 v = *(const uint4*)(xb + t * 8);
                const int k0 = q * 16 + t * 8;
                act[(k0 + 0) * COLS + b] = __uint_as_float(v.x << 16);
                act[(k0 + 1) * COLS + b] = __uint_as_float(v.x & 0xFFFF0000u);
                act[(k0 + 2) * COLS + b] = __uint_as_float(v.y << 16);
                act[(k0 + 3) * COLS + b] = __uint_as_float(v.y & 0xFFFF0000u);
                act[(k0 + 4) * COLS + b] = __uint_as_float(v.z << 16);
                act[(k0 + 5) * COLS + b] = __uint_as_float(v.z & 0xFFFF0000u);
                act[(k0 + 6) * COLS + b] = __uint_as_float(v.w << 16);
                act[(k0 + 7) * COLS + b] = __uint_as_float(v.w & 0xFFFF0000u);
            }
        } else {
            const float* xs = (const float*)xraw + (size_t)(c0 + b) * IN_SIZE + q * 16;
#pragma unroll
            for (int t = 0; t < 4; ++t) {
                const float4 v = *(const float4*)(xs + t * 4);
                const int k0 = q * 16 + t * 4;
                act[(k0 + 0) * COLS + b] = v.x;
                act[(k0 + 1) * COLS + b] = v.y;
                act[(k0 + 2) * COLS + b] = v.z;
                act[(k0 + 3) * COLS + b] = v.w;
            }
        }
    }
    // single wave: in-order DS pipeline -> no barrier anywhere

    // ---- 8-slot rotation: slot k holds node k, refilled 8 ahead ----
    uint4 spk[8]; float4 shz[8];
#pragma unroll
    for (int k = 0; k < 8; ++k) {
        spk[k] = pk[k * 16 + q];
        shz[k] = hzr[k * 8 + (q & 7)];
    }

    // ---- prologue: gathers n0->A, n1->B; reduce n0; gathers n2->A ----
    float A0, A1, B0, B1;
    { const uint4 g = spk[0];
      A0 = act[(int)g.x * COLS + c]; A1 = act[(int)g.y * COLS + c]; }
    { const uint4 g = spk[1];
      B0 = act[(int)g.x * COLS + c]; B1 = act[(int)g.y * COLS + c]; }
    float accA, accB;
    {
        const uint4 pv = spk[0];
        float a = A0 * __uint_as_float(pv.z);
        a = fmaf(A1, __uint_as_float(pv.w), a);
        a = dpp_add<0x121>(a); a = dpp_add<0x122>(a);
        a = dpp_add<0x124>(a); a = dpp_add<0x128>(a);
        accA = a;
    }
    { const uint4 g = spk[2];
      A0 = act[(int)g.x * COLS + c]; A1 = act[(int)g.y * COLS + c]; }

    float tp = 0.0f, tpp = 0.0f, tppp = 0.0f;

// OUT: compile-time 0/1 (output store). CLAMP: refill index clamping.
#define STEPM(i, K, S0, S1, ACCc, ACCn, OUT, CLAMP)                                    \
    {                                                                                  \
        /* reduce node i+1 (slot (K+1)&7; gathers issued 2 steps ago) */               \
        const uint4 pv = spk[((K) + 1) & 7];                                           \
        float a = S0 * __uint_as_float(pv.z);                                          \
        a = fmaf(S1, __uint_as_float(pv.w), a);                                        \
        a = dpp_add<0x121>(a); a = dpp_add<0x122>(a);                                  \
        a = dpp_add<0x124>(a); a = dpp_add<0x128>(a);                                  \
        ACCn = a;                                                                      \
        /* issue gathers node i+3 (before write(i): stale rows covered by h1..h3) */   \
        { const uint4 g = spk[((K) + 3) & 7];                                          \
          S0 = act[(int)g.x * COLS + c]; S1 = act[(int)g.y * COLS + c]; }              \
        /* finalize node i: critical chain = 1 fma (h.x*tp) + tanh */                  \
        const float4 h = shz[(K)];                                                     \
        float z = fmaf(h.z, tppp, ACCc);                                               \
        z = fmaf(h.y, tpp, z);                                                         \
        z = fmaf(h.x, tp, z);                                                          \
        const float s = __expf(-2.0f * fabsf(z));                                      \
        const float r = __builtin_amdgcn_rcpf(1.0f + s);                               \
        const float t = copysignf(fmaf(-s, r, r), z);                                  \
        if (q == 0) {                                                                  \
            act[(IN_SIZE + (i)) * COLS + c] = t;                                       \
            if (OUT) {                                                                 \
                const size_t o = (size_t)((i) - (N_NODES - OUT_SIZE)) * BATCH + c0 + c;\
                if (isbf16) outb[o] = f2bf_rne(t); else outf[o] = t;                   \
            }                                                                          \
        }                                                                              \
        /* refill slot K with node i+8 (2 vector loads, vmcnt-tracked) */              \
        { const int np = (CLAMP) ? (((i) + 8 < N_NODES) ? (i) + 8 : N_NODES - 1)       \
                                 : (i) + 8;                                            \
          spk[(K)] = pk[np * 16 + q];                                                  \
          shz[(K)] = hzr[np * 8 + (q & 7)]; }                                          \
        tppp = tpp; tpp = tp; tp = t;                                                  \
    }

    // main loop: nodes 0..1007 — no output check, no refill clamp (i+8 <= 1015)
#pragma unroll 1
    for (int ii = 0; ii < N_NODES - OUT_SIZE; ii += 8) {
        STEPM(ii + 0, 0, B0, B1, accA, accB, 0, 0)
        STEPM(ii + 1, 1, A0, A1, accB, accA, 0, 0)
        STEPM(ii + 2, 2, B0, B1, accA, accB, 0, 0)
        STEPM(ii + 3, 3, A0, A1, accB, accA, 0, 0)
        STEPM(ii + 4, 4, B0, B1, accA, accB, 0, 0)
        STEPM(ii + 5, 5, A0, A1, accB, accA, 0, 0)
        STEPM(ii + 6, 6, B0, B1, accA, accB, 0, 0)
        STEPM(ii + 7, 7, A0, A1, accB, accA, 0, 0)
    }
    // epilogue: nodes 1008..1023 — every node is an output node
    {
        const int ii = N_NODES - OUT_SIZE;       // 1008
        STEPM(ii + 0, 0, B0, B1, accA, accB, 1, 1)
        STEPM(ii + 1, 1, A0, A1, accB, accA, 1, 1)
        STEPM(ii + 2, 2, B0, B1, accA, accB, 1, 1)
        STEPM(ii + 3, 3, A0, A1, accB, accA, 1, 1)
        STEPM(ii + 4, 4, B0, B1, accA, accB, 1, 1)
        STEPM(ii + 5, 5, A0, A1, accB, accA, 1, 1)
        STEPM(ii + 6, 6, B0, B1, accA, accB, 1, 1)
        STEPM(ii + 7, 7, A0, A1, accB, accA, 1, 1)
        STEPM(ii + 8, 0, B0, B1, accA, accB, 1, 1)
        STEPM(ii + 9, 1, A0, A1, accB, accA, 1, 1)
        STEPM(ii + 10, 2, B0, B1, accA, accB, 1, 1)
        STEPM(ii + 11, 3, A0, A1, accB, accA, 1, 1)
        STEPM(ii + 12, 4, B0, B1, accA, accB, 1, 1)
        STEPM(ii + 13, 5, A0, A1, accB, accA, 1, 1)
        STEPM(ii + 14, 6, B0, B1, accA, accB, 1, 1)
        STEPM(ii + 15, 7, A0, A1, accB, accA, 1, 1)
    }
#undef STEPM
}

extern "C" void kernel_launch(void* const* d_in, const int* in_sizes, int n_in,
                              void* d_out, int out_size, void* d_ws, size_t ws_size,
                              hipStream_t stream) {
    const void* x   = d_in[0];                   // [BATCH][IN_SIZE]
    const void* w   = d_in[1];                   // [N_NODES][DEG]
    const int* idxs = (const int*)d_in[2];       // [N_NODES][DEG]

    uint4* pk   = (uint4*)d_ws;                                          // 256 KB
    float4* hzr = (float4*)((char*)d_ws + (size_t)N_NODES * 16 * 16);    // 128 KB
    int* flag   = (int*)((char*)d_ws + ((ws_size - 16) & ~(size_t)15));

    ne_detect<<<1, 64, 0, stream>>>(x, flag);
    ne_prep<<<32, 256, 0, stream>>>(w, idxs, pk, hzr, flag);

    // 4096 single-wave blocks, 20 KB LDS -> 8 blocks/CU (2 waves/SIMD),
    // 2 scheduling rounds, zero barriers.
    ne_forward<<<dim3(BATCH / COLS), dim3(64), 0, stream>>>(x, pk, hzr, d_out, flag);
}